// Round 1
// baseline (50.253 us; speedup 1.0000x reference)
//
#include <hip/hip_runtime.h>
#include <hip/hip_bf16.h>

typedef __bf16 bf16x8 __attribute__((ext_vector_type(8)));
typedef float  f32x4  __attribute__((ext_vector_type(4)));

static constexpr int NB   = 8;     // batch
static constexpr int S    = 2048;  // source rows
static constexpr int T    = 2048;  // target rows
static constexpr int D    = 128;   // feature dim
static constexpr int TILE = 128;   // output tile (square)

// 256 threads = 4 waves; each wave computes a 64x64 quadrant of the 128x128 tile.
__global__ __launch_bounds__(256, 2)
void cosim_mfma(const float* __restrict__ src, const float* __restrict__ tar,
                const int* __restrict__ mask_s, const int* __restrict__ mask_t,
                float* __restrict__ out)
{
    // [128 rows][16 x 16B], bf16, XOR-swizzled at 16B granularity: slot q stored at (q ^ (row&7))
    __shared__ uint4 ldsA[TILE * 16];
    __shared__ uint4 ldsB[TILE * 16];

    const int tt  = blockIdx.x;   // target tile index
    const int ts  = blockIdx.y;   // source tile index
    const int b   = blockIdx.z;
    const int tid = threadIdx.x;

    // ---------------- stage: load, L2-normalize, bf16-convert ----------------
    {
        const int row = tid >> 1;   // 0..127 (tile-local row)
        const int h   = tid & 1;    // which 64-float half of the row
        // A panel (source rows)
        {
            const float* p = src + ((size_t)(b * S + ts * TILE + row)) * D + h * 64;
            float4 v[16];
            float ss = 0.f;
            #pragma unroll
            for (int j = 0; j < 16; ++j) {
                v[j] = ((const float4*)p)[j];
                ss += v[j].x * v[j].x + v[j].y * v[j].y + v[j].z * v[j].z + v[j].w * v[j].w;
            }
            ss += __shfl_xor(ss, 1);                       // pair-reduce: full-row sumsq
            const float sc = 1.0f / fmaxf(sqrtf(ss), 1e-12f);
            #pragma unroll
            for (int i = 0; i < 8; ++i) {
                float4 u0 = v[2 * i], u1 = v[2 * i + 1];
                bf16x8 t;
                t[0] = (__bf16)(u0.x * sc); t[1] = (__bf16)(u0.y * sc);
                t[2] = (__bf16)(u0.z * sc); t[3] = (__bf16)(u0.w * sc);
                t[4] = (__bf16)(u1.x * sc); t[5] = (__bf16)(u1.y * sc);
                t[6] = (__bf16)(u1.z * sc); t[7] = (__bf16)(u1.w * sc);
                ldsA[row * 16 + ((h * 8 + i) ^ (row & 7))] = __builtin_bit_cast(uint4, t);
            }
        }
        // B panel (target rows)
        {
            const float* p = tar + ((size_t)(b * T + tt * TILE + row)) * D + h * 64;
            float4 v[16];
            float ss = 0.f;
            #pragma unroll
            for (int j = 0; j < 16; ++j) {
                v[j] = ((const float4*)p)[j];
                ss += v[j].x * v[j].x + v[j].y * v[j].y + v[j].z * v[j].z + v[j].w * v[j].w;
            }
            ss += __shfl_xor(ss, 1);
            const float sc = 1.0f / fmaxf(sqrtf(ss), 1e-12f);
            #pragma unroll
            for (int i = 0; i < 8; ++i) {
                float4 u0 = v[2 * i], u1 = v[2 * i + 1];
                bf16x8 t;
                t[0] = (__bf16)(u0.x * sc); t[1] = (__bf16)(u0.y * sc);
                t[2] = (__bf16)(u0.z * sc); t[3] = (__bf16)(u0.w * sc);
                t[4] = (__bf16)(u1.x * sc); t[5] = (__bf16)(u1.y * sc);
                t[6] = (__bf16)(u1.z * sc); t[7] = (__bf16)(u1.w * sc);
                ldsB[row * 16 + ((h * 8 + i) ^ (row & 7))] = __builtin_bit_cast(uint4, t);
            }
        }
    }
    __syncthreads();

    // ---------------- MFMA: wave (wr,wc) computes 64x64 ----------------
    const int lane = tid & 63;
    const int w    = tid >> 6;
    const int wr   = w >> 1;      // 0..1
    const int wc   = w & 1;       // 0..1
    const int r16  = lane & 15;   // fragment row/col within 16
    const int kg   = lane >> 4;   // k-group 0..3
    const int swz  = r16 & 7;     // swizzle key (row&7 == r16&7 here)

    f32x4 acc[4][4] = {};

    #pragma unroll
    for (int ks = 0; ks < 4; ++ks) {          // K = 4 * 32
        bf16x8 af[4], bfr[4];
        #pragma unroll
        for (int m = 0; m < 4; ++m) {
            const int rl = wr * 64 + m * 16 + r16;
            af[m]  = __builtin_bit_cast(bf16x8, ldsA[rl * 16 + ((ks * 4 + kg) ^ swz)]);
            const int cl = wc * 64 + m * 16 + r16;
            bfr[m] = __builtin_bit_cast(bf16x8, ldsB[cl * 16 + ((ks * 4 + kg) ^ swz)]);
        }
        #pragma unroll
        for (int m = 0; m < 4; ++m)
            #pragma unroll
            for (int n = 0; n < 4; ++n)
                acc[m][n] = __builtin_amdgcn_mfma_f32_16x16x32_bf16(af[m], bfr[n], acc[m][n], 0, 0, 0);
    }

    // ---------------- epilogue: ReLU + mask gate + dense store ----------------
    const int*  msS = mask_s + b * S + ts * TILE;
    const int*  msT = mask_t + b * T + tt * TILE;
    float*      po  = out + ((size_t)b * S + (size_t)ts * TILE) * T + (size_t)tt * TILE;

    float mrow[4][4];
    #pragma unroll
    for (int m = 0; m < 4; ++m)
        #pragma unroll
        for (int r = 0; r < 4; ++r) {
            const int rl = wr * 64 + m * 16 + kg * 4 + r;   // C/D: row = (lane>>4)*4 + reg
            mrow[m][r] = (msS[rl] != 0) ? 1.0f : 0.0f;
        }

    #pragma unroll
    for (int n = 0; n < 4; ++n) {
        const int cl = wc * 64 + n * 16 + r16;              // C/D: col = lane&15
        const float mt = (msT[cl] != 0) ? 1.0f : 0.0f;
        #pragma unroll
        for (int m = 0; m < 4; ++m) {
            #pragma unroll
            for (int r = 0; r < 4; ++r) {
                const int rl = wr * 64 + m * 16 + kg * 4 + r;
                const float v = fmaxf(acc[m][n][r], 0.0f);
                po[(size_t)rl * T + cl] = v * (mrow[m][r] * mt);
            }
        }
    }
}

extern "C" void kernel_launch(void* const* d_in, const int* in_sizes, int n_in,
                              void* d_out, int out_size, void* d_ws, size_t ws_size,
                              hipStream_t stream) {
    const float* src    = (const float*)d_in[0];
    const float* tar    = (const float*)d_in[1];
    const int*   mask_s = (const int*)d_in[2];
    const int*   mask_t = (const int*)d_in[3];
    float*       out    = (float*)d_out;

    dim3 grid(T / TILE, S / TILE, NB);   // (16, 16, 8)
    dim3 block(256);
    hipLaunchKernelGGL(cosim_mfma, grid, block, 0, stream, src, tar, mask_s, mask_t, out);
}

// Round 2
// 49.175 us; speedup vs baseline: 1.0219x; 1.0219x over previous
//
#include <hip/hip_runtime.h>
#include <hip/hip_bf16.h>

typedef __bf16 bf16x8 __attribute__((ext_vector_type(8)));
typedef float  f32x4  __attribute__((ext_vector_type(4)));

static constexpr int NB = 8;     // batch
static constexpr int S  = 2048;  // source rows
static constexpr int T  = 2048;  // target rows
static constexpr int D  = 128;   // feature dim
static constexpr int BT = 256;   // target-tile rows per block
static constexpr int BS = 256;   // source-tile rows per block

// 512 threads = 8 waves. Wave (wt,ws) computes a 64(t) x 128(s) sub-tile.
// Output D[t][s] via mfma(tar_frag, src_frag): lane holds col s = lane&15,
// rows t = (lane>>4)*4 + reg  -> per-lane float4 contiguous along t = out's
// innermost dim -> global_store_dwordx4.
__global__ __launch_bounds__(512, 2)
void cosim256(const float* __restrict__ src, const float* __restrict__ tar,
              const int* __restrict__ mask_s, const int* __restrict__ mask_t,
              float* __restrict__ out)
{
    // raw (un-normalized) bf16 panels, 16B-granule XOR swizzle: slot q at (q ^ (row&7))
    __shared__ uint4 ldsT[BT * 16];   // 64 KB  target panel
    __shared__ uint4 ldsS[BS * 16];   // 64 KB  source panel
    __shared__ float invT[BT];        // 1/||tar row||
    __shared__ float invS[BS];        // 1/||src row||

    // ---- XCD-chunked block swizzle: XCD k owns batch k's full 8x8 tile grid ----
    const int r  = blockIdx.x + 8 * (blockIdx.y + 8 * blockIdx.z);  // physical linear id
    const int l  = (r & 7) * 64 + (r >> 3);                          // bijective remap (512 = 8*64)
    const int tt = l & 7;
    const int ts = (l >> 3) & 7;
    const int b  = l >> 6;

    const int tid = threadIdx.x;

    // ---------------- stage: load f32 row, convert raw->bf16, sumsq ----------------
    {
        const int  row = tid & 255;
        const bool isS = (tid >= 256);
        const float* p = isS ? (src + ((size_t)(b * S + ts * BS + row)) * D)
                             : (tar + ((size_t)(b * T + tt * BT + row)) * D);
        uint4* panel = isS ? ldsS : ldsT;
        float ss = 0.f;
        #pragma unroll
        for (int q = 0; q < 16; ++q) {
            const float4 u0 = ((const float4*)p)[2 * q];
            const float4 u1 = ((const float4*)p)[2 * q + 1];
            ss += u0.x * u0.x + u0.y * u0.y + u0.z * u0.z + u0.w * u0.w
                + u1.x * u1.x + u1.y * u1.y + u1.z * u1.z + u1.w * u1.w;
            bf16x8 t;
            t[0] = (__bf16)u0.x; t[1] = (__bf16)u0.y; t[2] = (__bf16)u0.z; t[3] = (__bf16)u0.w;
            t[4] = (__bf16)u1.x; t[5] = (__bf16)u1.y; t[6] = (__bf16)u1.z; t[7] = (__bf16)u1.w;
            panel[row * 16 + (q ^ (row & 7))] = __builtin_bit_cast(uint4, t);
        }
        (isS ? invS : invT)[row] = 1.0f / fmaxf(sqrtf(ss), 1e-12f);
    }
    __syncthreads();

    // ---------------- MFMA: 128 MFMA per wave ----------------
    const int lane = tid & 63;
    const int w    = tid >> 6;
    const int wt   = w >> 1;      // 0..3  target strip (64 rows)
    const int ws   = w & 1;       // 0..1  source strip (128 rows)
    const int r16  = lane & 15;
    const int kg   = lane >> 4;   // 0..3
    const int swz  = r16 & 7;

    f32x4 acc[4][8] = {};

    #pragma unroll
    for (int ks = 0; ks < 4; ++ks) {           // K = 4 * 32
        bf16x8 at[4], bs[8];
        #pragma unroll
        for (int m = 0; m < 4; ++m) {
            const int rl = wt * 64 + m * 16 + r16;
            at[m] = __builtin_bit_cast(bf16x8, ldsT[rl * 16 + ((ks * 4 + kg) ^ swz)]);
        }
        #pragma unroll
        for (int n = 0; n < 8; ++n) {
            const int rl = ws * 128 + n * 16 + r16;
            bs[n] = __builtin_bit_cast(bf16x8, ldsS[rl * 16 + ((ks * 4 + kg) ^ swz)]);
        }
        #pragma unroll
        for (int m = 0; m < 4; ++m)
            #pragma unroll
            for (int n = 0; n < 8; ++n)
                acc[m][n] = __builtin_amdgcn_mfma_f32_16x16x32_bf16(at[m], bs[n], acc[m][n], 0, 0, 0);
    }

    // ---------------- epilogue: scale by invnorms, ReLU, mask, float4 store ----------------
    const int* msS = mask_s + b * S + ts * BS;
    const int* msT = mask_t + b * T + tt * BT;

    #pragma unroll
    for (int m = 0; m < 4; ++m) {
        const int tl = wt * 64 + m * 16 + kg * 4;          // this lane's t base (mult of 4)
        const int4   mt4 = *(const int4*)(msT + tl);
        const float4 it4 = *(const float4*)(&invT[tl]);
        const float g0 = mt4.x ? it4.x : 0.f;
        const float g1 = mt4.y ? it4.y : 0.f;
        const float g2 = mt4.z ? it4.z : 0.f;
        const float g3 = mt4.w ? it4.w : 0.f;
        #pragma unroll
        for (int n = 0; n < 8; ++n) {
            const int sl = ws * 128 + n * 16 + r16;        // this lane's s index
            const float fS = msS[sl] ? invS[sl] : 0.f;
            const f32x4 a = acc[m][n];
            float4 o;
            o.x = fmaxf(a[0], 0.f) * g0 * fS;
            o.y = fmaxf(a[1], 0.f) * g1 * fS;
            o.z = fmaxf(a[2], 0.f) * g2 * fS;
            o.w = fmaxf(a[3], 0.f) * g3 * fS;
            float* po = out + ((size_t)(b * S + ts * BS + sl)) * T + tt * BT + tl;
            *(float4*)po = o;
        }
    }
}

extern "C" void kernel_launch(void* const* d_in, const int* in_sizes, int n_in,
                              void* d_out, int out_size, void* d_ws, size_t ws_size,
                              hipStream_t stream) {
    const float* src    = (const float*)d_in[0];
    const float* tar    = (const float*)d_in[1];
    const int*   mask_s = (const int*)d_in[2];
    const int*   mask_t = (const int*)d_in[3];
    float*       out    = (float*)d_out;

    dim3 grid(T / BT, S / BS, NB);   // (8, 8, 8) = 512 blocks
    dim3 block(512);
    hipLaunchKernelGGL(cosim256, grid, block, 0, stream, src, tar, mask_s, mask_t, out);
}